// Round 10
// baseline (255.999 us; speedup 1.0000x reference)
//
#include <hip/hip_runtime.h>

static constexpr int NN = 100000;   // nodes
static constexpr int NE = 1600000;  // edges
static constexpr int BK = 391;      // buckets: bucket = dst >> 8 (256 nodes each)
static constexpr int BCAP = 4864;   // slots per bucket (mean 4096, sigma 64; +12 sigma)
static constexpr int NBA = 64;      // partition blocks (short atomic chains per counter)
static constexpr int CHUNK = NE / NBA;  // 25000 exactly

typedef _Float16 f16x8 __attribute__((ext_vector_type(8)));
typedef float f32x4 __attribute__((ext_vector_type(4)));

// ---- Phase A: partition edges into 391 dst-buckets; 64 blocks -> short atomic chains ----
__global__ __launch_bounds__(256) void binA_kernel(const int* __restrict__ src,
                                                   const int* __restrict__ dst,
                                                   const float* __restrict__ w,
                                                   int* __restrict__ bcursor,
                                                   long long* __restrict__ binned) {
  __shared__ int hist[BK];
  __shared__ int base[BK];
  const int t = threadIdx.x;
  const int e0 = blockIdx.x * CHUNK;
  const int e1 = min(e0 + CHUNK, NE);

  for (int i = t; i < BK; i += 256) hist[i] = 0;
  __syncthreads();
  for (int e = e0 + t; e < e1; e += 256) atomicAdd(&hist[dst[e] >> 8], 1);
  __syncthreads();
  for (int i = t; i < BK; i += 256) {
    int h = hist[i];
    base[i] = (h > 0) ? atomicAdd(&bcursor[i], h) : 0;
    hist[i] = 0;  // reuse as local cursor
  }
  __syncthreads();
  for (int e = e0 + t; e < e1; e += 256) {
    int d = dst[e];
    int bkt = d >> 8;
    int slot = atomicAdd(&hist[bkt], 1);
    int p = base[bkt] + slot;
    if (p < BCAP) {
      unsigned lo = (unsigned)src[e] | ((unsigned)(d & 255) << 20);
      unsigned long long ent = ((unsigned long long)__float_as_uint(w[e]) << 32) | lo;
      binned[(size_t)bkt * BCAP + p] = (long long)ent;
    }
  }
}

// ---- Phase B: per-bucket compact CSR (in place) + meta + dinv; no global atomics ----
__global__ __launch_bounds__(256) void buildB_kernel(const int* __restrict__ bcursor,
                                                     long long* __restrict__ binned,
                                                     int2* __restrict__ meta,
                                                     float* __restrict__ dinv) {
  __shared__ long long eb[BCAP];   // 38.9 KB
  __shared__ int cnt[256];
  __shared__ int off[256];
  __shared__ int cur[256];
  __shared__ float degs[256];
  __shared__ int wsum[4];
  const int b = blockIdx.x;
  const int t = threadIdx.x;
  const int m = min(bcursor[b], BCAP);
  long long* gb = binned + (size_t)b * BCAP;

  for (int i = t; i < m; i += 256) eb[i] = gb[i];
  cnt[t] = 0;
  degs[t] = 0.f;
  __syncthreads();

  for (int i = t; i < m; i += 256) {
    unsigned long long v = (unsigned long long)eb[i];
    int dl = (int)((v >> 20) & 255u);
    atomicAdd(&cnt[dl], 1);
    atomicAdd(&degs[dl], __uint_as_float((unsigned)(v >> 32)));
  }
  __syncthreads();

  // exclusive scan of cnt[256] (4 waves + wave offsets)
  const int lane = t & 63;
  const int c = cnt[t];
  int incl = c;
#pragma unroll
  for (int d2 = 1; d2 < 64; d2 <<= 1) {
    int v2 = __shfl_up(incl, d2, 64);
    if (lane >= d2) incl += v2;
  }
  if (lane == 63) wsum[t >> 6] = incl;
  __syncthreads();
  int wbase = 0;
#pragma unroll
  for (int ww = 0; ww < 4; ++ww) wbase += (ww < (t >> 6)) ? wsum[ww] : 0;
  const int myoff = wbase + incl - c;
  off[t] = myoff;
  cur[t] = 0;
  __syncthreads();

  // place into compact CSR, in place over the bucket region (L2-hot)
  for (int i = t; i < m; i += 256) {
    long long v = eb[i];
    int dl = (int)(((unsigned long long)v >> 20) & 255u);
    int slot = atomicAdd(&cur[dl], 1);
    gb[off[dl] + slot] = v;
  }

  const int n = b * 256 + t;
  if (n < NN) {
    meta[n] = make_int2(b * BCAP + myoff, c);
    dinv[n] = rsqrtf(degs[t] + 1.0f);
  }
}

// ---- W1,W2 -> fp16 fragment-order buffers (one kernel) ----
// wf[((t*4+ks)*64+l)*8+j] = W[k][n], n = t*16+(l&15), k = ks*32+(l>>4)*8+j
__global__ void wfrag_kernel(const float* __restrict__ W1, const float* __restrict__ W2,
                             _Float16* __restrict__ wf1, _Float16* __restrict__ wf2) {
  int i = blockIdx.x * blockDim.x + threadIdx.x;
  const float* W;
  _Float16* wf;
  int N, idx;
  if (i < 128 * 128) {
    W = W1; wf = wf1; N = 128; idx = i;
  } else if (i < 128 * 128 + 64 * 128) {
    W = W2; wf = wf2; N = 64; idx = i - 128 * 128;
  } else return;
  int j = idx & 7;
  int l = (idx >> 3) & 63;
  int ks = (idx >> 9) & 3;
  int t = idx >> 11;
  int n = t * 16 + (l & 15);
  int k = ks * 32 + (l >> 4) * 8 + j;
  wf[idx] = (_Float16)W[k * N + n];
}

// ---- MFMA GEMM: H[NN,N] fp16 = X[NN,128] @ W ; no LDS, no barriers ----
template <int N, typename AT>
__global__ __launch_bounds__(256) void mfma_gemm_kernel(const AT* __restrict__ X,
                                                        const _Float16* __restrict__ wf,
                                                        _Float16* __restrict__ H) {
  constexpr int NT = N / 16;
  const int w = threadIdx.x >> 6;
  const int l = threadIdx.x & 63;
  const int row0 = (blockIdx.x * 4 + w) * 16;
  const int arow = row0 + (l & 15);
  const int kb = (l >> 4) * 8;

  f16x8 a[4];
  if (arow < NN) {
    const AT* xp = X + (size_t)arow * 128 + kb;
#pragma unroll
    for (int ks = 0; ks < 4; ++ks) {
      if constexpr (sizeof(AT) == 4) {
        float4 lo = *(const float4*)(xp + ks * 32);
        float4 hi = *(const float4*)(xp + ks * 32 + 4);
        f16x8 v;
        v[0] = (_Float16)lo.x; v[1] = (_Float16)lo.y;
        v[2] = (_Float16)lo.z; v[3] = (_Float16)lo.w;
        v[4] = (_Float16)hi.x; v[5] = (_Float16)hi.y;
        v[6] = (_Float16)hi.z; v[7] = (_Float16)hi.w;
        a[ks] = v;
      } else {
        a[ks] = *(const f16x8*)(xp + ks * 32);
      }
    }
  } else {
    f16x8 z;
#pragma unroll
    for (int j = 0; j < 8; ++j) z[j] = (_Float16)0.f;
#pragma unroll
    for (int ks = 0; ks < 4; ++ks) a[ks] = z;
  }

  f32x4 acc[NT];
#pragma unroll
  for (int t = 0; t < NT; ++t) acc[t] = {0.f, 0.f, 0.f, 0.f};

  const _Float16* wp = wf + l * 8;
#pragma unroll
  for (int t = 0; t < NT; ++t) {
#pragma unroll
    for (int ks = 0; ks < 4; ++ks) {
      f16x8 b = *(const f16x8*)(wp + (size_t)(t * 4 + ks) * 512);
      acc[t] = __builtin_amdgcn_mfma_f32_16x16x32_f16(a[ks], b, acc[t], 0, 0, 0);
    }
  }

  // C/D layout: col = lane&15, row = (lane>>4)*4 + reg
  const int r0 = row0 + (l >> 4) * 4;
  const int c0 = l & 15;
#pragma unroll
  for (int t = 0; t < NT; ++t) {
#pragma unroll
    for (int r = 0; r < 4; ++r) {
      int row = r0 + r;
      if (row < NN) H[(size_t)row * N + t * 16 + c0] = (_Float16)acc[t][r];
    }
  }
}

// ------- gather + self-loop + bias + relu; H fp16 (16B/lane), fp32 accum, 2-deep -------
// out[n] = relu( dinv[n] * sum_e(dinv[src]*w*H[src]) + H[n]*dinv[n]^2 + b )
template <int F, typename OT>
__global__ __launch_bounds__(256) void gather_kernel(
    const int2* __restrict__ meta, const long long* __restrict__ csr,
    const _Float16* __restrict__ H, const float* __restrict__ dinv,
    const float* __restrict__ b, OT* __restrict__ out) {
  constexpr int TPN = F / 8;  // lanes per node: 16 (F=128) or 8 (F=64)
  constexpr int NPB = 256 / TPN;
  const int t = threadIdx.x;
  const int node = blockIdx.x * NPB + t / TPN;
  if (node >= NN) return;
  const int f = (t % TPN) * 8;

  const int2 mt = meta[node];
  const int lo = mt.x;
  const int hi = mt.x + mt.y;
  const float di = dinv[node];
  const float sl = di * di;

  f16x8 hs = *(const f16x8*)(H + (size_t)node * F + f);
  float c[8], aA[8], aB[8];
#pragma unroll
  for (int j = 0; j < 8; ++j) {
    c[j] = fmaf((float)hs[j], sl, b[f + j]);
    aA[j] = 0.f;
    aB[j] = 0.f;
  }

  int i = lo;
  for (; i + 1 < hi; i += 2) {
    unsigned long long v0 = (unsigned long long)csr[i];
    unsigned long long v1 = (unsigned long long)csr[i + 1];
    int s0 = (int)(v0 & 0x1FFFFu);
    int s1 = (int)(v1 & 0x1FFFFu);
    float n0 = dinv[s0] * __uint_as_float((unsigned)(v0 >> 32));
    float n1 = dinv[s1] * __uint_as_float((unsigned)(v1 >> 32));
    f16x8 h0 = *(const f16x8*)(H + (size_t)s0 * F + f);
    f16x8 h1 = *(const f16x8*)(H + (size_t)s1 * F + f);
#pragma unroll
    for (int j = 0; j < 8; ++j) {
      aA[j] = fmaf((float)h0[j], n0, aA[j]);
      aB[j] = fmaf((float)h1[j], n1, aB[j]);
    }
  }
  if (i < hi) {
    unsigned long long v0 = (unsigned long long)csr[i];
    int s0 = (int)(v0 & 0x1FFFFu);
    float n0 = dinv[s0] * __uint_as_float((unsigned)(v0 >> 32));
    f16x8 h0 = *(const f16x8*)(H + (size_t)s0 * F + f);
#pragma unroll
    for (int j = 0; j < 8; ++j) aA[j] = fmaf((float)h0[j], n0, aA[j]);
  }

  float o[8];
#pragma unroll
  for (int j = 0; j < 8; ++j) o[j] = fmaxf(fmaf(aA[j] + aB[j], di, c[j]), 0.f);

  if constexpr (sizeof(OT) == 2) {
    f16x8 v;
#pragma unroll
    for (int j = 0; j < 8; ++j) v[j] = (_Float16)o[j];
    *(f16x8*)(out + (size_t)node * F + f) = v;
  } else {
    float4 v0 = make_float4(o[0], o[1], o[2], o[3]);
    float4 v1 = make_float4(o[4], o[5], o[6], o[7]);
    *(float4*)(out + (size_t)node * F + f) = v0;
    *(float4*)(out + (size_t)node * F + f + 4) = v1;
  }
}

extern "C" void kernel_launch(void* const* d_in, const int* in_sizes, int n_in,
                              void* d_out, int out_size, void* d_ws, size_t ws_size,
                              hipStream_t stream) {
  const float* x  = (const float*)d_in[0];
  const int*   ei = (const int*)d_in[1];
  const float* ew = (const float*)d_in[2];
  const float* W1 = (const float*)d_in[3];
  const float* b1 = (const float*)d_in[4];
  const float* W2 = (const float*)d_in[5];
  const float* b2 = (const float*)d_in[6];
  float* out = (float*)d_out;

  const int* src = ei;        // edge_index[0]
  const int* dst = ei + NE;   // edge_index[1]

  // workspace layout (f32 units):
  // bcursor (512 i32) | dinv (NN f32) | meta (NN int2) | binned/csr (BK*BCAP i64)
  // | h1 (NN*128 fp16) | a1 (NN*128 fp16) | wf1 | wf2
  float* wsf        = (float*)d_ws;
  int*   bcursor    = (int*)wsf;                              // 512
  float* dinv       = wsf + 512;                              // NN
  int2*  meta       = (int2*)(wsf + 512 + NN);                // 2*NN
  long long* binned = (long long*)(wsf + 512 + 3 * NN);       // BK*BCAP i64
  float* fbase      = wsf + 512 + 3 * NN + (size_t)BK * BCAP * 2;
  _Float16* h1      = (_Float16*)fbase;                       // NN*128 fp16
  _Float16* a1      = (_Float16*)(fbase + (size_t)NN * 64);   // NN*128 fp16
  _Float16* wf1     = (_Float16*)(fbase + (size_t)NN * 128);  // 16384 fp16
  _Float16* wf2     = wf1 + 16384;                            // 8192 fp16
  _Float16* h2      = h1;  // reuse after layer-1 gather consumes h1

  hipMemsetAsync(bcursor, 0, 512 * sizeof(int), stream);

  binA_kernel<<<NBA, 256, 0, stream>>>(src, dst, ew, bcursor, binned);
  buildB_kernel<<<BK, 256, 0, stream>>>(bcursor, binned, meta, dinv);
  wfrag_kernel<<<96, 256, 0, stream>>>(W1, W2, wf1, wf2);

  // layer 1: h1 = fp16(x@W1) ; a1 = fp16(relu(dinv*gather(h1) + h1*dinv^2 + b1))
  mfma_gemm_kernel<128, float><<<(NN + 63) / 64, 256, 0, stream>>>(x, wf1, h1);
  gather_kernel<128, _Float16><<<(NN * 16 + 255) / 256, 256, 0, stream>>>(meta, binned,
                                                                          h1, dinv, b1, a1);

  // layer 2: h2 = fp16(a1@W2) ; out = relu(dinv*gather(h2) + h2*dinv^2 + b2)
  mfma_gemm_kernel<64, _Float16><<<(NN + 63) / 64, 256, 0, stream>>>(a1, wf2, h2);
  gather_kernel<64, float><<<(NN * 8 + 255) / 256, 256, 0, stream>>>(meta, binned,
                                                                     h2, dinv, b2, out);
}

// Round 11
// 192.829 us; speedup vs baseline: 1.3276x; 1.3276x over previous
//
#include <hip/hip_runtime.h>

static constexpr int NN = 100000;   // nodes
static constexpr int NE = 1600000;  // edges
static constexpr int BK = 391;      // buckets: bucket = dst >> 8 (256 nodes each)
static constexpr int BK2 = 392;     // padded even
static constexpr int BCAP = 4864;   // slots per bucket (mean 4096, sigma 64; +12 sigma)
static constexpr int NBA = 512;     // partition blocks
static constexpr int CHUNK = NE / NBA;  // 3125 exactly

typedef _Float16 f16x8 __attribute__((ext_vector_type(8)));
typedef float f32x4 __attribute__((ext_vector_type(4)));

// ---- Phase A: partition edges into dst-buckets with block-local counting sort ----
// Writes go out bucket-sorted -> coalesced runs instead of 8B random scatter.
__global__ __launch_bounds__(512) void binA_kernel(const int* __restrict__ src,
                                                   const int* __restrict__ dst,
                                                   const float* __restrict__ w,
                                                   int* __restrict__ bcursor,
                                                   long long* __restrict__ binned) {
  __shared__ int hist[BK2];        // counts, later reused as local cursors
  __shared__ int base[BK];         // per-bucket global (bucket-relative) claim
  __shared__ int localoff[BK2];    // exclusive scan of hist
  __shared__ int wsum[4];
  __shared__ unsigned long long ebuf[CHUNK];   // 25 KB sorted entries
  __shared__ unsigned short bkts[CHUNK];       // 6.25 KB bucket id per slot
  const int t = threadIdx.x;
  const int e0 = blockIdx.x * CHUNK;
  const int e1 = e0 + CHUNK;

  for (int i = t; i < BK2; i += 512) hist[i] = 0;
  __syncthreads();
  for (int e = e0 + t; e < e1; e += 512) atomicAdd(&hist[dst[e] >> 8], 1);
  __syncthreads();
  for (int i = t; i < BK; i += 512) base[i] = atomicAdd(&bcursor[i], hist[i]);

  // exclusive scan of hist[0..391]: thread t<196 owns buckets {2t, 2t+1}
  int h0 = 0, h1 = 0, c = 0;
  if (t < 196) {
    h0 = hist[2 * t];
    h1 = hist[2 * t + 1];
    c = h0 + h1;
  }
  if (t < 256) {
    const int lane = t & 63;
    int incl = c;
#pragma unroll
    for (int d2 = 1; d2 < 64; d2 <<= 1) {
      int v2 = __shfl_up(incl, d2, 64);
      if (lane >= d2) incl += v2;
    }
    if (lane == 63) wsum[t >> 6] = incl;
    __syncthreads();
    int wbase = 0;
#pragma unroll
    for (int ww = 0; ww < 4; ++ww) wbase += (ww < (t >> 6)) ? wsum[ww] : 0;
    if (t < 196) {
      int ex = wbase + incl - c;
      localoff[2 * t] = ex;
      localoff[2 * t + 1] = ex + h0;
    }
  } else {
    __syncthreads();
  }
  __syncthreads();
  for (int i = t; i < BK2; i += 512) hist[i] = 0;  // reuse as cursors
  __syncthreads();

  // place entries into LDS sorted by bucket
  for (int e = e0 + t; e < e1; e += 512) {
    int d = dst[e];
    int bkt = d >> 8;
    int slot = atomicAdd(&hist[bkt], 1);
    int pos = localoff[bkt] + slot;
    unsigned lo = (unsigned)src[e] | ((unsigned)(d & 255) << 20);
    ebuf[pos] = ((unsigned long long)__float_as_uint(w[e]) << 32) | lo;
    bkts[pos] = (unsigned short)bkt;
  }
  __syncthreads();

  // flush: consecutive threads hit consecutive slots of each bucket run
  for (int pos = t; pos < CHUNK; pos += 512) {
    int bkt = bkts[pos];
    int g = base[bkt] + (pos - localoff[bkt]);
    if (g < BCAP) binned[(size_t)bkt * BCAP + g] = (long long)ebuf[pos];
  }
}

// ---- Phase B: per-bucket compact CSR (in place) + meta + dinv; no global atomics ----
__global__ __launch_bounds__(256) void buildB_kernel(const int* __restrict__ bcursor,
                                                     long long* __restrict__ binned,
                                                     int2* __restrict__ meta,
                                                     float* __restrict__ dinv) {
  __shared__ long long eb[BCAP];   // 38.9 KB
  __shared__ int cnt[256];
  __shared__ int off[256];
  __shared__ int cur[256];
  __shared__ float degs[256];
  __shared__ int wsum[4];
  const int b = blockIdx.x;
  const int t = threadIdx.x;
  const int m = min(bcursor[b], BCAP);
  long long* gb = binned + (size_t)b * BCAP;

  for (int i = t; i < m; i += 256) eb[i] = gb[i];
  cnt[t] = 0;
  degs[t] = 0.f;
  __syncthreads();

  for (int i = t; i < m; i += 256) {
    unsigned long long v = (unsigned long long)eb[i];
    int dl = (int)((v >> 20) & 255u);
    atomicAdd(&cnt[dl], 1);
    atomicAdd(&degs[dl], __uint_as_float((unsigned)(v >> 32)));
  }
  __syncthreads();

  // exclusive scan of cnt[256] (4 waves + wave offsets)
  const int lane = t & 63;
  const int c = cnt[t];
  int incl = c;
#pragma unroll
  for (int d2 = 1; d2 < 64; d2 <<= 1) {
    int v2 = __shfl_up(incl, d2, 64);
    if (lane >= d2) incl += v2;
  }
  if (lane == 63) wsum[t >> 6] = incl;
  __syncthreads();
  int wbase = 0;
#pragma unroll
  for (int ww = 0; ww < 4; ++ww) wbase += (ww < (t >> 6)) ? wsum[ww] : 0;
  const int myoff = wbase + incl - c;
  off[t] = myoff;
  cur[t] = 0;
  __syncthreads();

  // place into compact CSR, in place over the bucket region (L2-hot)
  for (int i = t; i < m; i += 256) {
    long long v = eb[i];
    int dl = (int)(((unsigned long long)v >> 20) & 255u);
    int slot = atomicAdd(&cur[dl], 1);
    gb[off[dl] + slot] = v;
  }

  const int n = b * 256 + t;
  if (n < NN) {
    meta[n] = make_int2(b * BCAP + myoff, c);
    dinv[n] = rsqrtf(degs[t] + 1.0f);
  }
}

// ---- W1,W2 -> fp16 fragment-order buffers (one kernel) ----
// wf[((t*4+ks)*64+l)*8+j] = W[k][n], n = t*16+(l&15), k = ks*32+(l>>4)*8+j
__global__ void wfrag_kernel(const float* __restrict__ W1, const float* __restrict__ W2,
                             _Float16* __restrict__ wf1, _Float16* __restrict__ wf2) {
  int i = blockIdx.x * blockDim.x + threadIdx.x;
  const float* W;
  _Float16* wf;
  int N, idx;
  if (i < 128 * 128) {
    W = W1; wf = wf1; N = 128; idx = i;
  } else if (i < 128 * 128 + 64 * 128) {
    W = W2; wf = wf2; N = 64; idx = i - 128 * 128;
  } else return;
  int j = idx & 7;
  int l = (idx >> 3) & 63;
  int ks = (idx >> 9) & 3;
  int t = idx >> 11;
  int n = t * 16 + (l & 15);
  int k = ks * 32 + (l >> 4) * 8 + j;
  wf[idx] = (_Float16)W[k * N + n];
}

// ---- MFMA GEMM: H[NN,N] fp16 = X[NN,128] @ W ; no LDS, no barriers ----
template <int N, typename AT>
__global__ __launch_bounds__(256) void mfma_gemm_kernel(const AT* __restrict__ X,
                                                        const _Float16* __restrict__ wf,
                                                        _Float16* __restrict__ H) {
  constexpr int NT = N / 16;
  const int w = threadIdx.x >> 6;
  const int l = threadIdx.x & 63;
  const int row0 = (blockIdx.x * 4 + w) * 16;
  const int arow = row0 + (l & 15);
  const int kb = (l >> 4) * 8;

  f16x8 a[4];
  if (arow < NN) {
    const AT* xp = X + (size_t)arow * 128 + kb;
#pragma unroll
    for (int ks = 0; ks < 4; ++ks) {
      if constexpr (sizeof(AT) == 4) {
        float4 lo = *(const float4*)(xp + ks * 32);
        float4 hi = *(const float4*)(xp + ks * 32 + 4);
        f16x8 v;
        v[0] = (_Float16)lo.x; v[1] = (_Float16)lo.y;
        v[2] = (_Float16)lo.z; v[3] = (_Float16)lo.w;
        v[4] = (_Float16)hi.x; v[5] = (_Float16)hi.y;
        v[6] = (_Float16)hi.z; v[7] = (_Float16)hi.w;
        a[ks] = v;
      } else {
        a[ks] = *(const f16x8*)(xp + ks * 32);
      }
    }
  } else {
    f16x8 z;
#pragma unroll
    for (int j = 0; j < 8; ++j) z[j] = (_Float16)0.f;
#pragma unroll
    for (int ks = 0; ks < 4; ++ks) a[ks] = z;
  }

  f32x4 acc[NT];
#pragma unroll
  for (int t = 0; t < NT; ++t) acc[t] = {0.f, 0.f, 0.f, 0.f};

  const _Float16* wp = wf + l * 8;
#pragma unroll
  for (int t = 0; t < NT; ++t) {
#pragma unroll
    for (int ks = 0; ks < 4; ++ks) {
      f16x8 b = *(const f16x8*)(wp + (size_t)(t * 4 + ks) * 512);
      acc[t] = __builtin_amdgcn_mfma_f32_16x16x32_f16(a[ks], b, acc[t], 0, 0, 0);
    }
  }

  // C/D layout: col = lane&15, row = (lane>>4)*4 + reg
  const int r0 = row0 + (l >> 4) * 4;
  const int c0 = l & 15;
#pragma unroll
  for (int t = 0; t < NT; ++t) {
#pragma unroll
    for (int r = 0; r < 4; ++r) {
      int row = r0 + r;
      if (row < NN) H[(size_t)row * N + t * 16 + c0] = (_Float16)acc[t][r];
    }
  }
}

// ------- gather + self-loop + bias + relu; H fp16 (16B/lane), fp32 accum, 2-deep -------
// out[n] = relu( dinv[n] * sum_e(dinv[src]*w*H[src]) + H[n]*dinv[n]^2 + b )
template <int F, typename OT>
__global__ __launch_bounds__(256) void gather_kernel(
    const int2* __restrict__ meta, const long long* __restrict__ csr,
    const _Float16* __restrict__ H, const float* __restrict__ dinv,
    const float* __restrict__ b, OT* __restrict__ out) {
  constexpr int TPN = F / 8;  // lanes per node: 16 (F=128) or 8 (F=64)
  constexpr int NPB = 256 / TPN;
  const int t = threadIdx.x;
  const int node = blockIdx.x * NPB + t / TPN;
  if (node >= NN) return;
  const int f = (t % TPN) * 8;

  const int2 mt = meta[node];
  const int lo = mt.x;
  const int hi = mt.x + mt.y;
  const float di = dinv[node];
  const float sl = di * di;

  f16x8 hs = *(const f16x8*)(H + (size_t)node * F + f);
  float c[8], aA[8], aB[8];
#pragma unroll
  for (int j = 0; j < 8; ++j) {
    c[j] = fmaf((float)hs[j], sl, b[f + j]);
    aA[j] = 0.f;
    aB[j] = 0.f;
  }

  int i = lo;
  for (; i + 1 < hi; i += 2) {
    unsigned long long v0 = (unsigned long long)csr[i];
    unsigned long long v1 = (unsigned long long)csr[i + 1];
    int s0 = (int)(v0 & 0x1FFFFu);
    int s1 = (int)(v1 & 0x1FFFFu);
    float n0 = dinv[s0] * __uint_as_float((unsigned)(v0 >> 32));
    float n1 = dinv[s1] * __uint_as_float((unsigned)(v1 >> 32));
    f16x8 h0 = *(const f16x8*)(H + (size_t)s0 * F + f);
    f16x8 h1 = *(const f16x8*)(H + (size_t)s1 * F + f);
#pragma unroll
    for (int j = 0; j < 8; ++j) {
      aA[j] = fmaf((float)h0[j], n0, aA[j]);
      aB[j] = fmaf((float)h1[j], n1, aB[j]);
    }
  }
  if (i < hi) {
    unsigned long long v0 = (unsigned long long)csr[i];
    int s0 = (int)(v0 & 0x1FFFFu);
    float n0 = dinv[s0] * __uint_as_float((unsigned)(v0 >> 32));
    f16x8 h0 = *(const f16x8*)(H + (size_t)s0 * F + f);
#pragma unroll
    for (int j = 0; j < 8; ++j) aA[j] = fmaf((float)h0[j], n0, aA[j]);
  }

  float o[8];
#pragma unroll
  for (int j = 0; j < 8; ++j) o[j] = fmaxf(fmaf(aA[j] + aB[j], di, c[j]), 0.f);

  if constexpr (sizeof(OT) == 2) {
    f16x8 v;
#pragma unroll
    for (int j = 0; j < 8; ++j) v[j] = (_Float16)o[j];
    *(f16x8*)(out + (size_t)node * F + f) = v;
  } else {
    float4 v0 = make_float4(o[0], o[1], o[2], o[3]);
    float4 v1 = make_float4(o[4], o[5], o[6], o[7]);
    *(float4*)(out + (size_t)node * F + f) = v0;
    *(float4*)(out + (size_t)node * F + f + 4) = v1;
  }
}

extern "C" void kernel_launch(void* const* d_in, const int* in_sizes, int n_in,
                              void* d_out, int out_size, void* d_ws, size_t ws_size,
                              hipStream_t stream) {
  const float* x  = (const float*)d_in[0];
  const int*   ei = (const int*)d_in[1];
  const float* ew = (const float*)d_in[2];
  const float* W1 = (const float*)d_in[3];
  const float* b1 = (const float*)d_in[4];
  const float* W2 = (const float*)d_in[5];
  const float* b2 = (const float*)d_in[6];
  float* out = (float*)d_out;

  const int* src = ei;        // edge_index[0]
  const int* dst = ei + NE;   // edge_index[1]

  // workspace layout (f32 units):
  // bcursor (512 i32) | dinv (NN f32) | meta (NN int2) | binned/csr (BK*BCAP i64)
  // | h1 (NN*128 fp16) | a1 (NN*128 fp16) | wf1 | wf2
  float* wsf        = (float*)d_ws;
  int*   bcursor    = (int*)wsf;                              // 512
  float* dinv       = wsf + 512;                              // NN
  int2*  meta       = (int2*)(wsf + 512 + NN);                // 2*NN
  long long* binned = (long long*)(wsf + 512 + 3 * NN);       // BK*BCAP i64
  float* fbase      = wsf + 512 + 3 * NN + (size_t)BK * BCAP * 2;
  _Float16* h1      = (_Float16*)fbase;                       // NN*128 fp16
  _Float16* a1      = (_Float16*)(fbase + (size_t)NN * 64);   // NN*128 fp16
  _Float16* wf1     = (_Float16*)(fbase + (size_t)NN * 128);  // 16384 fp16
  _Float16* wf2     = wf1 + 16384;                            // 8192 fp16
  _Float16* h2      = h1;  // reuse after layer-1 gather consumes h1

  hipMemsetAsync(bcursor, 0, 512 * sizeof(int), stream);

  binA_kernel<<<NBA, 512, 0, stream>>>(src, dst, ew, bcursor, binned);
  buildB_kernel<<<BK, 256, 0, stream>>>(bcursor, binned, meta, dinv);
  wfrag_kernel<<<96, 256, 0, stream>>>(W1, W2, wf1, wf2);

  // layer 1: h1 = fp16(x@W1) ; a1 = fp16(relu(dinv*gather(h1) + h1*dinv^2 + b1))
  mfma_gemm_kernel<128, float><<<(NN + 63) / 64, 256, 0, stream>>>(x, wf1, h1);
  gather_kernel<128, _Float16><<<(NN * 16 + 255) / 256, 256, 0, stream>>>(meta, binned,
                                                                          h1, dinv, b1, a1);

  // layer 2: h2 = fp16(a1@W2) ; out = relu(dinv*gather(h2) + h2*dinv^2 + b2)
  mfma_gemm_kernel<64, _Float16><<<(NN + 63) / 64, 256, 0, stream>>>(a1, wf2, h2);
  gather_kernel<64, float><<<(NN * 8 + 255) / 256, 256, 0, stream>>>(meta, binned,
                                                                     h2, dinv, b2, out);
}